// Round 4
// baseline (10668.535 us; speedup 1.0000x reference)
//
#include <hip/hip_runtime.h>
#include <hip/hip_bf16.h>

// Problem constants (B=256, T=512, H=512, IN=1, future=64)
#define TT  512
#define BB  256
#define HH  512
#define FUT 64
#define NBLK 128           // 2 roles x 32 unit-groups x 2 batch-groups

// Output dtype FP32. Beacons: float 2^(20+code)*(1+m/128):
//  0: n_in!=22  1: in_sizes mismatch @m  2: ws too small  6: out_size wrong
// r16 = r15 protocol + anti-hang hardening (bounded spins, restored tid0
// drain). r15 coherence protocol:
//   - h producers: global_store_dwordx4 sc0 sc1  (write straight to IC)
//   - h consumers: PLAIN cached loads (L1/L2 allocate -> per-XCD dedup of
//     the 32x broadcast read; L2 serves ~20MB/phase at 34TB/s)
//   - GBAR epilogue: fence(acquire, "agent") = s_waitcnt + buffer_inv
//     (invalidates L1 + XCD L2) once per phase, so cached h lines can
//     never be stale across the barrier.
//   - EPI drains stores per-thread (vmcnt is per-wave).
// Spin guards: ~16M iterations (~100ms) then break — converts any protocol
// failure into passed:false + counters instead of a dead container.
// r14 structure kept: layer-split roles, operand-swapped MFMA, in-lane EPI.

struct Hdr { int dtflag; };

typedef __attribute__((ext_vector_type(8))) short short8;
typedef __attribute__((ext_vector_type(4))) float floatx4;

#define OFF_CTR   4096
#define OFF_W     8192
#define WSZ       ((size_t)2048*512*2)          // 2MB bf16 matrix
#define OFF_H     (OFF_W + 6*WSZ)
#define HSZ       ((size_t)BB*HH*2)             // 256KB bf16 state
#define NEED_WS   (OFF_H + 4*HSZ)               // ~13.6MB

#define SPIN_CAP  (1L << 24)

__device__ __forceinline__ float bf2f(short s) {
  unsigned u = ((unsigned)(unsigned short)s) << 16;
  return __builtin_bit_cast(float, u);
}
__device__ __forceinline__ short f2bf(float f) {
  unsigned u = __builtin_bit_cast(unsigned, f);
  u = u + 0x7FFFu + ((u >> 16) & 1u);
  return (short)(u >> 16);
}
__device__ __forceinline__ float ldf(const void* p, long i, int dt) {
  return dt ? ((const float*)p)[i] : bf2f(((const short*)p)[i]);
}
// cached 16B load (manual vmcnt discipline — result ready after WAITV)
__device__ __forceinline__ short8 cld16(const short* p) {
  short8 v;
  asm volatile("global_load_dwordx4 %0, %1, off"
               : "=v"(v) : "v"(p));
  return v;
}
// 16B store straight to the coherence point (IC), bypassing L1/L2
__device__ __forceinline__ void cohst16(short* p, short8 v) {
  asm volatile("global_store_dwordx4 %0, %1, off sc0 sc1"
               :: "v"(p), "v"(v) : "memory");
}
// counted wait + hard scheduling fence (rule #18: keep MFMA below the wait)
#define WAITV(N) do { asm volatile("s_waitcnt vmcnt(" #N ")" ::: "memory"); \
                      __builtin_amdgcn_sched_barrier(0); } while (0)

__global__ void beacon_kernel(float* dout, float v) {
  if (threadIdx.x == 0) dout[0] = v;
}

__global__ __launch_bounds__(256) void probe1_kernel(const void* w, Hdr* hdr) {
  const int tid = threadIdx.x;
  const short* s = (const short*)w;
  float mx = 0.f;
  #pragma unroll
  for (int i = 0; i < 16; ++i) {
    float v = fabsf(bf2f(s[tid * 16 + i]));
    if (!(v == v)) v = 1e30f;
    mx = fmaxf(mx, v);
  }
  #pragma unroll
  for (int off = 32; off > 0; off >>= 1) mx = fmaxf(mx, __shfl_down(mx, off));
  __shared__ float wmax[4];
  if ((tid & 63) == 0) wmax[tid >> 6] = mx;
  __syncthreads();
  if (tid == 0) {
    float m = fmaxf(fmaxf(wmax[0], wmax[1]), fmaxf(wmax[2], wmax[3]));
    hdr->dtflag = (m > 1000.f) ? 1 : 0;
  }
}

__global__ __launch_bounds__(256) void cvt_kernel(const void* src, short* dst,
                                                  const Hdr* hdr) {
  const int dt = hdr->dtflag;
  const long i = ((long)blockIdx.x * 256 + threadIdx.x);
  if (dt) {
    const float4 v = ((const float4*)src)[i];
    short4 o;
    o.x = f2bf(v.x); o.y = f2bf(v.y); o.z = f2bf(v.z); o.w = f2bf(v.w);
    ((short4*)dst)[i] = o;
  } else {
    ((short4*)dst)[i] = ((const short4*)src)[i];
  }
}

// Persistent 2-layer LSTM, layer-split roles, LDS weights, L2-dedup coh.
__global__ __launch_bounds__(256, 1) void lstm_persist(
    const void* __restrict__ x,
    const void* __restrict__ w_ih0, const void* __restrict__ b_ih0,
    const void* __restrict__ b_hh0, const void* __restrict__ b_ih1,
    const void* __restrict__ b_hh1, const void* __restrict__ fc_w,
    const void* __restrict__ fc_b,  const void* __restrict__ pw_ih0,
    const void* __restrict__ pb_ih0, const void* __restrict__ pb_hh0,
    const void* __restrict__ pb_ih1, const void* __restrict__ pb_hh1,
    const void* __restrict__ pfc_w, const void* __restrict__ pfc_b,
    const short* __restrict__ Whh0, const short* __restrict__ Wih1,
    const short* __restrict__ Whh1, const short* __restrict__ pWhh0,
    const short* __restrict__ pWih1, const short* __restrict__ pWhh1,
    short* H0a, short* H0b, short* H1a, short* H1b,
    int* ctr, const Hdr* __restrict__ hdr, float* __restrict__ dout)
{
  const int dt  = hdr->dtflag;
  const int tid = threadIdx.x;
  const int role = blockIdx.x & 1;         // 0 = layer0, 1 = layer1
  const int bg   = (blockIdx.x >> 1) & 1;  // 0..1
  const int ug   = blockIdx.x >> 2;        // 0..31
  const int U0   = ug * 16;
  const int B0   = bg * 128;
  int* grpArr = ctr + 32 + (blockIdx.x >> 4) * 32;        // arrive line
  int* grpRel = ctr + 32 + (blockIdx.x >> 4) * 32 + 16;   // release line
  const int isMaster = (blockIdx.x & 15) == 0;            // 8 masters

  // 128KB weights: [slot][kseg(64)][row(64)][8]; row = unit_local*4 + gate,
  // kseg -> k = kseg*8. role0 uses slot0; role1 uses slot0(ih)+slot1(hh).
  __shared__ __align__(16) short Wl[2][64][64][8];
  __shared__ __align__(16) short hbuf[128][16];  // 4KB h repack
  __shared__ float bs[64];                       // bias, idx = u*4+gate
  __shared__ float wih[64];                      // w_ih col (L0 only)
  __shared__ float obuf[128];

  const int lane = tid & 63;
  const int wv   = tid >> 6;           // 32-batch half per wave
  const int ln   = lane & 15;          // batch-in-tile AND W-row-in-tile
  const int q    = lane >> 4;          // k-slice / unit-in-quad
  const long abase = (long)(B0 + wv*32 + ln) * 512 + q*8;

  // per-lane cell state for this role's layer: [mt][nt] ->
  // unit = U0 + mt*4 + q, batch = B0 + wv*32 + nt*16 + ln
  float cst[4][2] = {{0.f,0.f},{0.f,0.f},{0.f,0.f},{0.f,0.f}};

  short *h0c = H0a, *h0n = H0b, *h1c = H1a, *h1n = H1b;
  int ph = 0;

// stage one 64KB slot, global-coalesced (ds write conflicts are one-time)
#define STAGE16(SLOT, WG)                                                    \
  for (int i = tid; i < 4096; i += 256) {                                    \
    const int ks_ = i & 63, r_ = i >> 6;                                     \
    const long gr = (long)((r_ & 3) * 512 + U0 + (r_ >> 2)) * 512 + ks_ * 8; \
    *(short8*)&Wl[SLOT][ks_][r_][0] = *(const short8*)((WG) + gr);           \
  }

#define BIAS16(B1, B2, WIHP)                                                 \
  if (tid < 64) {                                                            \
    const long j = (long)(tid & 3) * 512 + U0 + (tid >> 2);                  \
    bs[tid] = ldf((B1), j, dt) + ldf((B2), j, dt);                           \
    wih[tid] = (WIHP) ? ldf((const void*)(WIHP), j, dt) : 0.f;               \
  }

#define ZACC(A)                                                              \
  _Pragma("unroll") for (int mt_ = 0; mt_ < 4; ++mt_)                        \
    _Pragma("unroll") for (int nt_ = 0; nt_ < 2; ++nt_)                      \
      A[mt_][nt_] = (floatx4){0.f, 0.f, 0.f, 0.f};

#define LOFF(KB, NT) ((long)(NT) * 16 * 512 + (KB) * 32)

// single-stream pass: K=512 as 16 kb; 4 groups x (4kb x 2nt) = 8 loads
#define GSEG1N(AP, ACC)                                                      \
  { const short* ap_ = (AP) + abase;                                         \
    short8 abuf[2][8];                                                       \
    _Pragma("unroll")                                                        \
    for (int u_ = 0; u_ < 8; ++u_)                                           \
      abuf[0][u_] = cld16(ap_ + LOFF(u_ >> 1, u_ & 1));                      \
    _Pragma("unroll")                                                        \
    for (int g = 0; g < 4; ++g) {                                            \
      if (g < 3) {                                                           \
        _Pragma("unroll")                                                    \
        for (int u_ = 0; u_ < 8; ++u_)                                       \
          abuf[(g+1)&1][u_] = cld16(ap_ + LOFF((g+1)*4 + (u_>>1), u_&1));    \
        WAITV(8);                                                            \
      } else { WAITV(0); }                                                   \
      _Pragma("unroll")                                                      \
      for (int kk = 0; kk < 4; ++kk) {                                       \
        const int kb = g*4 + kk;                                             \
        _Pragma("unroll")                                                    \
        for (int mt = 0; mt < 4; ++mt) {                                     \
          short8 wf = *(const short8*)&Wl[0][kb*4 + q][mt*16 + ln][0];       \
          _Pragma("unroll")                                                  \
          for (int nt = 0; nt < 2; ++nt)                                     \
            ACC[mt][nt] = __builtin_amdgcn_mfma_f32_16x16x32_bf16(           \
                wf, abuf[g&1][kk*2 + nt], ACC[mt][nt], 0, 0, 0);             \
        }                                                                    \
      }                                                                      \
    } }

// dual-stream pass: gates += Wl[0]*h(AP0) + Wl[1]*h(AP1); one latency
// exposure, 8 groups x (2kb x 2nt x 2streams) = 8 loads each
#define GSEG2N(AP0, AP1, ACC)                                                \
  { const short* p0_ = (AP0) + abase;                                        \
    const short* p1_ = (AP1) + abase;                                        \
    short8 abuf[2][8]; /* [buf][kk*4 + stream*2 + nt] */                     \
    _Pragma("unroll")                                                        \
    for (int u_ = 0; u_ < 2; ++u_) {                                         \
      abuf[0][u_*4+0] = cld16(p0_ + LOFF(u_, 0));                            \
      abuf[0][u_*4+1] = cld16(p0_ + LOFF(u_, 1));                            \
      abuf[0][u_*4+2] = cld16(p1_ + LOFF(u_, 0));                            \
      abuf[0][u_*4+3] = cld16(p1_ + LOFF(u_, 1));                            \
    }                                                                        \
    _Pragma("unroll")                                                        \
    for (int g = 0; g < 8; ++g) {                                            \
      if (g < 7) {                                                           \
        _Pragma("unroll")                                                    \
        for (int u_ = 0; u_ < 2; ++u_) {                                     \
          const int kb = (g+1)*2 + u_;                                       \
          abuf[(g+1)&1][u_*4+0] = cld16(p0_ + LOFF(kb, 0));                  \
          abuf[(g+1)&1][u_*4+1] = cld16(p0_ + LOFF(kb, 1));                  \
          abuf[(g+1)&1][u_*4+2] = cld16(p1_ + LOFF(kb, 0));                  \
          abuf[(g+1)&1][u_*4+3] = cld16(p1_ + LOFF(kb, 1));                  \
        }                                                                    \
        WAITV(8);                                                            \
      } else { WAITV(0); }                                                   \
      _Pragma("unroll")                                                      \
      for (int kk = 0; kk < 2; ++kk) {                                       \
        const int kb = g*2 + kk;                                             \
        _Pragma("unroll")                                                    \
        for (int mt = 0; mt < 4; ++mt) {                                     \
          short8 w0 = *(const short8*)&Wl[0][kb*4 + q][mt*16 + ln][0];       \
          short8 w1 = *(const short8*)&Wl[1][kb*4 + q][mt*16 + ln][0];       \
          _Pragma("unroll")                                                  \
          for (int nt = 0; nt < 2; ++nt) {                                   \
            ACC[mt][nt] = __builtin_amdgcn_mfma_f32_16x16x32_bf16(           \
                w0, abuf[g&1][kk*4 + nt], ACC[mt][nt], 0, 0, 0);             \
            ACC[mt][nt] = __builtin_amdgcn_mfma_f32_16x16x32_bf16(           \
                w1, abuf[g&1][kk*4 + 2 + nt], ACC[mt][nt], 0, 0, 0);         \
          }                                                                  \
        }                                                                    \
      }                                                                      \
    } }

// in-lane epilogue: lane holds gates i,f,g,o of (unit=U0+mt*4+q, batch) in
// ACC[mt][nt][0..3]. MODE 0: sv = x[b][TV]; 1: none; 2: sv = obuf[b].
// Repack h through 4KB LDS, then coalesced 16B IC stores; per-thread drain
// (vmcnt is per-wave — every wave must order its own stores vs barrier).
#define EPI16(ACC, MODE, TV, HOUT)                                           \
  { float sv[2];                                                             \
    _Pragma("unroll")                                                        \
    for (int nt = 0; nt < 2; ++nt) {                                         \
      const int bl = wv*32 + nt*16 + ln;                                     \
      sv[nt] = ((MODE) == 0) ? ldf(x, (long)(B0 + bl)*TT + (TV), dt)         \
             : ((MODE) == 2) ? obuf[bl] : 0.f;                               \
    }                                                                        \
    _Pragma("unroll")                                                        \
    for (int mt = 0; mt < 4; ++mt) {                                         \
      const int u = mt*4 + q;                                                \
      _Pragma("unroll")                                                      \
      for (int nt = 0; nt < 2; ++nt) {                                       \
        float gi = ACC[mt][nt][0] + bs[u*4+0];                               \
        float gf = ACC[mt][nt][1] + bs[u*4+1];                               \
        float gg = ACC[mt][nt][2] + bs[u*4+2];                               \
        float go = ACC[mt][nt][3] + bs[u*4+3];                               \
        if ((MODE) != 1) {                                                   \
          gi += sv[nt]*wih[u*4+0]; gf += sv[nt]*wih[u*4+1];                  \
          gg += sv[nt]*wih[u*4+2]; go += sv[nt]*wih[u*4+3];                  \
        }                                                                    \
        const float I = 1.f/(1.f+expf(-gi));                                 \
        const float F = 1.f/(1.f+expf(-gf));                                 \
        const float G = tanhf(gg);                                           \
        const float O = 1.f/(1.f+expf(-go));                                 \
        const float cn = F*cst[mt][nt] + I*G;                                \
        cst[mt][nt] = cn;                                                    \
        hbuf[wv*32 + nt*16 + ln][u] = f2bf(O * tanhf(cn));                   \
      }                                                                      \
    }                                                                        \
    __syncthreads();                                                         \
    { const int b_ = tid >> 1, hf_ = tid & 1;                                \
      short8 hv = *(const short8*)&hbuf[b_][hf_*8];                          \
      cohst16((HOUT) + (long)(B0 + b_)*512 + U0 + hf_*8, hv);                \
      asm volatile("s_waitcnt vmcnt(0)" ::: "memory"); } }

// bounded spin: breaks after SPIN_CAP iterations instead of hanging the
// container — a broken protocol then shows as passed:false with counters.
#define SPIN(COND)                                                           \
  { long guard_ = 0;                                                         \
    while (COND) {                                                           \
      __builtin_amdgcn_s_sleep(1);                                           \
      if (++guard_ > SPIN_CAP) break;                                        \
    } }

// barrier: 8 groups of 16, per-group release line.
// Exit fence (acquire, agent) = s_waitcnt + buffer_inv: invalidates this
// CU's L1 and this XCD's L2 so the phase's cached h reads are never stale.
#define GBAR()                                                               \
  { __syncthreads();                                                         \
    ++ph;                                                                    \
    if (tid == 0) {                                                          \
      asm volatile("s_waitcnt vmcnt(0)" ::: "memory");                       \
      __hip_atomic_fetch_add(grpArr, 1, __ATOMIC_RELAXED,                    \
                             __HIP_MEMORY_SCOPE_SYSTEM);                     \
      if (isMaster) {                                                        \
        SPIN(__hip_atomic_load(grpArr, __ATOMIC_RELAXED,                     \
                               __HIP_MEMORY_SCOPE_SYSTEM) < ph * 16);        \
        __hip_atomic_fetch_add(ctr, 1, __ATOMIC_RELAXED,                     \
                               __HIP_MEMORY_SCOPE_SYSTEM);                   \
        SPIN(__hip_atomic_load(ctr, __ATOMIC_RELAXED,                        \
                               __HIP_MEMORY_SCOPE_SYSTEM) < ph * 8);         \
        __hip_atomic_store(grpRel, ph, __ATOMIC_RELAXED,                     \
                           __HIP_MEMORY_SCOPE_SYSTEM);                       \
      } else {                                                               \
        SPIN(__hip_atomic_load(grpRel, __ATOMIC_RELAXED,                     \
                               __HIP_MEMORY_SCOPE_SYSTEM) < ph);             \
      }                                                                      \
    }                                                                        \
    __syncthreads();                                                         \
    __builtin_amdgcn_fence(__ATOMIC_ACQUIRE, "agent");                       \
  }

// pipelined head (2-deep, single latency): only L0-role runs this
#define HEADP(H1C, FW, FB, S)                                                \
  { const int hb = tid >> 1, hf = tid & 1;                                   \
    const short* hp = (H1C) + (long)(B0 + hb)*512 + hf*256;                  \
    float sum = 0.f;                                                         \
    short8 hbu[2][8];                                                        \
    _Pragma("unroll")                                                        \
    for (int i = 0; i < 8; ++i) hbu[0][i] = cld16(hp + i*8);                 \
    _Pragma("unroll")                                                        \
    for (int g4 = 0; g4 < 4; ++g4) {                                         \
      if (g4 < 3) {                                                          \
        _Pragma("unroll")                                                    \
        for (int i = 0; i < 8; ++i)                                          \
          hbu[(g4+1)&1][i] = cld16(hp + ((g4+1)*8 + i)*8);                   \
        WAITV(8);                                                            \
      } else { WAITV(0); }                                                   \
      _Pragma("unroll")                                                      \
      for (int i = 0; i < 8; ++i)                                            \
        _Pragma("unroll")                                                    \
        for (int j = 0; j < 8; ++j)                                          \
          sum += bf2f(hbu[g4&1][i][j]) *                                     \
                 ldf((FW), hf*256 + (g4*8+i)*8 + j, dt);                     \
    }                                                                        \
    sum += __shfl_xor(sum, 1);                                               \
    if (hf == 0) {                                                           \
      float o = sum + ldf((FB), 0, dt);                                      \
      obuf[hb] = o;                                                          \
      if (ug == 0) dout[(long)(B0 + hb)*FUT + (S)] = o;                      \
    }                                                                        \
    __syncthreads();                                                         \
  }

  // ---- one-time staging: warmup weights + biases ----
  if (role == 0) {
    STAGE16(0, Whh0);
    BIAS16(b_ih0, b_hh0, w_ih0);
  } else {
    STAGE16(0, Wih1); STAGE16(1, Whh1);
    BIAS16(b_ih1, b_hh1, (const void*)0);
  }
  __syncthreads();

  // ---- warmup: phase t = L0(t) on role0 || L1(t-1) on role1 ----
  for (int t = 0; t < TT; ++t) {
    if (role == 0) {
      floatx4 a[4][2]; ZACC(a);
      GSEG1N(h0c, a);
      EPI16(a, 0, t, h0n);
    } else if (t > 0) {
      floatx4 a[4][2]; ZACC(a);
      GSEG2N(h0c, h1c, a);
      EPI16(a, 1, 0, h1n);
    }
    GBAR();
    { short* t_ = h0c; h0c = h0n; h0n = t_; }
    if (t > 0) { short* t_ = h1c; h1c = h1n; h1n = t_; }
  }
  // final L1(511)
  if (role == 1) {
    floatx4 a[4][2]; ZACC(a);
    GSEG2N(h0c, h1c, a);
    EPI16(a, 1, 0, h1n);
  }
  GBAR();
  { short* t_ = h1c; h1c = h1n; h1n = t_; }
  if (role == 0) HEADP(h1c, fc_w, fc_b, 0);

  // ---- transition: stage decode weights + biases (block-local) ----
  if (role == 0) {
    STAGE16(0, pWhh0);
    BIAS16(pb_ih0, pb_hh0, pw_ih0);
  } else {
    STAGE16(0, pWih1); STAGE16(1, pWhh1);
    BIAS16(pb_ih1, pb_hh1, (const void*)0);
  }
  __syncthreads();

  // ---- decode: 63 steps, 2 barriers each; c-state carried in-lane ----
  for (int s = 1; s < FUT; ++s) {
    if (role == 0) {
      floatx4 a[4][2]; ZACC(a);
      GSEG1N(h0c, a);
      EPI16(a, 2, 0, h0n);
    }
    GBAR();
    { short* t_ = h0c; h0c = h0n; h0n = t_; }
    if (role == 1) {
      floatx4 a[4][2]; ZACC(a);
      GSEG2N(h0c, h1c, a);
      EPI16(a, 1, 0, h1n);
    }
    GBAR();
    { short* t_ = h1c; h1c = h1n; h1n = t_; }
    if (role == 0) HEADP(h1c, pfc_w, pfc_b, s);
  }
#undef STAGE16
#undef BIAS16
#undef ZACC
#undef LOFF
#undef GSEG1N
#undef GSEG2N
#undef EPI16
#undef SPIN
#undef GBAR
#undef HEADP
}

extern "C" void kernel_launch(void* const* d_in, const int* in_sizes, int n_in,
                              void* d_out, int out_size, void* d_ws, size_t ws_size,
                              hipStream_t stream) {
  float* dout = (float*)d_out;

  static const int exp_sizes[22] = {
    131072, 1, 2048, 1048576, 2048, 2048, 1048576, 1048576, 2048, 2048,
    512, 1, 2048, 1048576, 2048, 2048, 1048576, 1048576, 2048, 2048, 512, 1};
  int code = -1, m = 0;
  if (n_in != 22) { code = 0; m = n_in & 127; }
  else {
    for (int i = 0; i < 22; ++i)
      if (in_sizes[i] != exp_sizes[i]) { code = 1; m = i; break; }
  }
  if (code < 0 && out_size != BB * FUT) { code = 6; m = (out_size >> 8) & 127; }
  if (code < 0 && (d_ws == nullptr || ws_size < NEED_WS)) {
    code = 2; m = (int)(ws_size >> 20); if (m > 127) m = 127;
  }
  if (code >= 0) {
    float v = ldexpf(1.f + (float)m / 128.f, 20 + code);
    beacon_kernel<<<dim3(1), dim3(64), 0, stream>>>(dout, v);
    return;
  }

  const void* x      = d_in[0];
  const void* w_ih0  = d_in[2];
  const void* w_hh0  = d_in[3];
  const void* b_ih0  = d_in[4];
  const void* b_hh0  = d_in[5];
  const void* w_ih1  = d_in[6];
  const void* w_hh1  = d_in[7];
  const void* b_ih1  = d_in[8];
  const void* b_hh1  = d_in[9];
  const void* fc_w   = d_in[10];
  const void* fc_b   = d_in[11];
  const void* pw_ih0 = d_in[12];
  const void* pw_hh0 = d_in[13];
  const void* pb_ih0 = d_in[14];
  const void* pb_hh0 = d_in[15];
  const void* pw_ih1 = d_in[16];
  const void* pw_hh1 = d_in[17];
  const void* pb_ih1 = d_in[18];
  const void* pb_hh1 = d_in[19];
  const void* pfc_w  = d_in[20];
  const void* pfc_b  = d_in[21];

  char* ws = (char*)d_ws;
  Hdr* hdr = (Hdr*)ws;
  int* ctr = (int*)(ws + OFF_CTR);
  short* Wc[6];
  for (int i = 0; i < 6; ++i) Wc[i] = (short*)(ws + OFF_W + (size_t)i*WSZ);
  short* H0a = (short*)(ws + OFF_H);
  short* H0b = (short*)(ws + OFF_H + HSZ);
  short* H1a = (short*)(ws + OFF_H + 2*HSZ);
  short* H1b = (short*)(ws + OFF_H + 3*HSZ);

  hipMemsetAsync(ws, 0, 8192, stream);          // hdr + barrier counters
  hipMemsetAsync(H0a, 0, HSZ, stream);
  hipMemsetAsync(H1a, 0, HSZ, stream);
  probe1_kernel<<<dim3(1), dim3(256), 0, stream>>>(w_hh0, hdr);

  dim3 cg(1024), cb(256);
  cvt_kernel<<<cg, cb, 0, stream>>>(w_hh0,  Wc[0], hdr);
  cvt_kernel<<<cg, cb, 0, stream>>>(w_ih1,  Wc[1], hdr);
  cvt_kernel<<<cg, cb, 0, stream>>>(w_hh1,  Wc[2], hdr);
  cvt_kernel<<<cg, cb, 0, stream>>>(pw_hh0, Wc[3], hdr);
  cvt_kernel<<<cg, cb, 0, stream>>>(pw_ih1, Wc[4], hdr);
  cvt_kernel<<<cg, cb, 0, stream>>>(pw_hh1, Wc[5], hdr);

  lstm_persist<<<dim3(NBLK), dim3(256), 0, stream>>>(
      x, w_ih0, b_ih0, b_hh0, b_ih1, b_hh1, fc_w, fc_b,
      pw_ih0, pb_ih0, pb_hh0, pb_ih1, pb_hh1, pfc_w, pfc_b,
      Wc[0], Wc[1], Wc[2], Wc[3], Wc[4], Wc[5],
      H0a, H0b, H1a, H1b, ctr, hdr, dout);
}

// Round 5
// 7207.684 us; speedup vs baseline: 1.4802x; 1.4802x over previous
//
#include <hip/hip_runtime.h>
#include <hip/hip_bf16.h>

// Problem constants (B=256, T=512, H=512, IN=1, future=64)
#define TT  512
#define BB  256
#define HH  512
#define FUT 64
#define NBLK 128           // 2 roles x 32 unit-groups x 2 batch-groups

// Output dtype FP32. Beacons: float 2^(20+code)*(1+m/128):
//  0: n_in!=22  1: in_sizes mismatch @m  2: ws too small  6: out_size wrong
// r17: TLP fix + distributed head.
//  - 512 threads / 8 waves -> 2 waves/SIMD (r13-r16 ran 1 wave/SIMD: every
//    vmcnt/barrier/transcendental stall was fully exposed; Occupancy 6%).
//  - head via per-step partial sums: role1 computes fc_w . h1 from its
//    in-register h values, atomicAdd into oacc[s][batch]; role0 reads one
//    4B value next phase. HEAD's 16-load dot product leaves the critical
//    path; role0 no longer touches h1 at all.
//  - coherence = r14 protocol (sc0sc1 stores AND loads, no fence, caches
//    never hold h). r15/r16 cached+invalidate protocol REGRESSED (-23%).
//  - bounded spins kept (hang -> passed:false, not dead container).

struct Hdr { int dtflag; };

typedef __attribute__((ext_vector_type(8))) short short8;
typedef __attribute__((ext_vector_type(4))) float floatx4;

#define OFF_CTR   4096
#define OFF_W     8192
#define WSZ       ((size_t)2048*512*2)          // 2MB bf16 matrix
#define OFF_H     (OFF_W + 6*WSZ)
#define HSZ       ((size_t)BB*HH*2)             // 256KB bf16 state
#define OFF_OA    (OFF_H + 4*HSZ)               // o accumulators
#define OASZ      ((size_t)FUT*BB*4)            // 64KB fp32
#define NEED_WS   (OFF_OA + OASZ)               // ~13.7MB

#define SPIN_CAP  (1L << 24)

__device__ __forceinline__ float bf2f(short s) {
  unsigned u = ((unsigned)(unsigned short)s) << 16;
  return __builtin_bit_cast(float, u);
}
__device__ __forceinline__ short f2bf(float f) {
  unsigned u = __builtin_bit_cast(unsigned, f);
  u = u + 0x7FFFu + ((u >> 16) & 1u);
  return (short)(u >> 16);
}
__device__ __forceinline__ float ldf(const void* p, long i, int dt) {
  return dt ? ((const float*)p)[i] : bf2f(((const short*)p)[i]);
}
// 16B coherence-point load/store: dwordx4 with sc0 sc1 (bypass L1/L2,
// IC is the coherence point). Result not ready until manual WAITV.
__device__ __forceinline__ short8 cohld16(const short* p) {
  short8 v;
  asm volatile("global_load_dwordx4 %0, %1, off sc0 sc1"
               : "=v"(v) : "v"(p));
  return v;
}
__device__ __forceinline__ void cohst16(short* p, short8 v) {
  asm volatile("global_store_dwordx4 %0, %1, off sc0 sc1"
               :: "v"(p), "v"(v) : "memory");
}
// counted wait + hard scheduling fence (rule #18: keep MFMA below the wait)
#define WAITV(N) do { asm volatile("s_waitcnt vmcnt(" #N ")" ::: "memory"); \
                      __builtin_amdgcn_sched_barrier(0); } while (0)

__global__ void beacon_kernel(float* dout, float v) {
  if (threadIdx.x == 0) dout[0] = v;
}

__global__ __launch_bounds__(256) void probe1_kernel(const void* w, Hdr* hdr) {
  const int tid = threadIdx.x;
  const short* s = (const short*)w;
  float mx = 0.f;
  #pragma unroll
  for (int i = 0; i < 16; ++i) {
    float v = fabsf(bf2f(s[tid * 16 + i]));
    if (!(v == v)) v = 1e30f;
    mx = fmaxf(mx, v);
  }
  #pragma unroll
  for (int off = 32; off > 0; off >>= 1) mx = fmaxf(mx, __shfl_down(mx, off));
  __shared__ float wmax[4];
  if ((tid & 63) == 0) wmax[tid >> 6] = mx;
  __syncthreads();
  if (tid == 0) {
    float m = fmaxf(fmaxf(wmax[0], wmax[1]), fmaxf(wmax[2], wmax[3]));
    hdr->dtflag = (m > 1000.f) ? 1 : 0;
  }
}

__global__ __launch_bounds__(256) void cvt_kernel(const void* src, short* dst,
                                                  const Hdr* hdr) {
  const int dt = hdr->dtflag;
  const long i = ((long)blockIdx.x * 256 + threadIdx.x);
  if (dt) {
    const float4 v = ((const float4*)src)[i];
    short4 o;
    o.x = f2bf(v.x); o.y = f2bf(v.y); o.z = f2bf(v.z); o.w = f2bf(v.w);
    ((short4*)dst)[i] = o;
  } else {
    ((short4*)dst)[i] = ((const short4*)src)[i];
  }
}

// Persistent 2-layer LSTM, layer-split roles, 8 waves, distributed head.
__global__ __launch_bounds__(512, 1) void lstm_persist(
    const void* __restrict__ x,
    const void* __restrict__ w_ih0, const void* __restrict__ b_ih0,
    const void* __restrict__ b_hh0, const void* __restrict__ b_ih1,
    const void* __restrict__ b_hh1, const void* __restrict__ fc_w,
    const void* __restrict__ fc_b,  const void* __restrict__ pw_ih0,
    const void* __restrict__ pb_ih0, const void* __restrict__ pb_hh0,
    const void* __restrict__ pb_ih1, const void* __restrict__ pb_hh1,
    const void* __restrict__ pfc_w, const void* __restrict__ pfc_b,
    const short* __restrict__ Whh0, const short* __restrict__ Wih1,
    const short* __restrict__ Whh1, const short* __restrict__ pWhh0,
    const short* __restrict__ pWih1, const short* __restrict__ pWhh1,
    short* H0a, short* H0b, short* H1a, short* H1b,
    float* oA, int* ctr, const Hdr* __restrict__ hdr,
    float* __restrict__ dout)
{
  const int dt  = hdr->dtflag;
  const int tid = threadIdx.x;
  const int role = blockIdx.x & 1;         // 0 = layer0, 1 = layer1
  const int bg   = (blockIdx.x >> 1) & 1;  // 0..1
  const int ug   = blockIdx.x >> 2;        // 0..31
  const int U0   = ug * 16;
  const int B0   = bg * 128;
  int* grpArr = ctr + 32 + (blockIdx.x >> 4) * 32;        // arrive line
  int* grpRel = ctr + 32 + (blockIdx.x >> 4) * 32 + 16;   // release line
  const int isMaster = (blockIdx.x & 15) == 0;            // 8 masters

  // 128KB weights: [slot][kseg(64)][row(64)][8]; row = unit_local*4 + gate.
  // role0 uses slot0; role1 uses slot0(ih)+slot1(hh).
  __shared__ __align__(16) short Wl[2][64][64][8];
  __shared__ __align__(16) short hbuf[128][16];  // 4KB h repack
  __shared__ float bs[64];                       // bias, idx = u*4+gate
  __shared__ float wih[64];                      // w_ih col (L0 only)

  const int lane = tid & 63;
  const int wv   = tid >> 6;           // wave 0..7: 16-batch slice each
  const int ln   = lane & 15;          // batch-in-tile AND W-row-in-tile
  const int q    = lane >> 4;          // k-slice / unit-in-quad
  const int bl   = wv*16 + ln;         // batch-in-block 0..127
  const long abase = (long)(B0 + bl) * 512 + q*8;

  // per-lane cell state: unit = U0 + mt*4 + q, batch = B0 + bl
  float cst[4] = {0.f, 0.f, 0.f, 0.f};
  float fwk[4] = {0.f, 0.f, 0.f, 0.f};   // head weight col (role1)

  short *h0c = H0a, *h0n = H0b, *h1c = H1a, *h1n = H1b;
  int ph = 0;

// stage one 64KB slot, global-coalesced
#define STAGE16(SLOT, WG)                                                    \
  for (int i = tid; i < 4096; i += 512) {                                    \
    const int ks_ = i & 63, r_ = i >> 6;                                     \
    const long gr = (long)((r_ & 3) * 512 + U0 + (r_ >> 2)) * 512 + ks_ * 8; \
    *(short8*)&Wl[SLOT][ks_][r_][0] = *(const short8*)((WG) + gr);           \
  }

#define BIAS16(B1, B2, WIHP)                                                 \
  if (tid < 64) {                                                            \
    const long j = (long)(tid & 3) * 512 + U0 + (tid >> 2);                  \
    bs[tid] = ldf((B1), j, dt) + ldf((B2), j, dt);                           \
    wih[tid] = (WIHP) ? ldf((const void*)(WIHP), j, dt) : 0.f;               \
  }

#define FWLOAD(FWP)                                                          \
  { _Pragma("unroll")                                                        \
    for (int mt = 0; mt < 4; ++mt)                                           \
      fwk[mt] = ldf((FWP), U0 + mt*4 + q, dt); }

#define ZACC(A)                                                              \
  _Pragma("unroll") for (int mt_ = 0; mt_ < 4; ++mt_)                        \
    A[mt_] = (floatx4){0.f, 0.f, 0.f, 0.f};

// single-stream pass: 16 kb, 2 groups of 8, 2-deep
#define GSEG1N(AP, ACC)                                                      \
  { const short* ap_ = (AP) + abase;                                         \
    short8 abuf[2][8];                                                       \
    _Pragma("unroll")                                                        \
    for (int i = 0; i < 8; ++i) abuf[0][i] = cohld16(ap_ + i*32);            \
    _Pragma("unroll")                                                        \
    for (int g = 0; g < 2; ++g) {                                            \
      if (g == 0) {                                                          \
        _Pragma("unroll")                                                    \
        for (int i = 0; i < 8; ++i)                                          \
          abuf[1][i] = cohld16(ap_ + (8+i)*32);                              \
        WAITV(8);                                                            \
      } else { WAITV(0); }                                                   \
      _Pragma("unroll")                                                      \
      for (int kk = 0; kk < 8; ++kk) {                                       \
        const int kb = g*8 + kk;                                             \
        _Pragma("unroll")                                                    \
        for (int mt = 0; mt < 4; ++mt) {                                     \
          short8 wf = *(const short8*)&Wl[0][kb*4 + q][mt*16 + ln][0];       \
          ACC[mt] = __builtin_amdgcn_mfma_f32_16x16x32_bf16(                 \
              wf, abuf[g][kk], ACC[mt], 0, 0, 0);                            \
        }                                                                    \
      }                                                                      \
    } }

// dual-stream pass: Wl[0]*h(AP0) + Wl[1]*h(AP1); 4 groups of 8, 2-deep
#define GSEG2N(AP0, AP1, ACC)                                                \
  { const short* p0_ = (AP0) + abase;                                        \
    const short* p1_ = (AP1) + abase;                                        \
    short8 abuf[2][8];                                                       \
    _Pragma("unroll")                                                        \
    for (int i = 0; i < 8; ++i) abuf[0][i] = cohld16(p0_ + i*32);            \
    _Pragma("unroll")                                                        \
    for (int g = 0; g < 4; ++g) {                                            \
      if (g < 3) {                                                           \
        const short* np_ = ((g+1)&1) ? p1_ : p0_;                            \
        const int nb_ = ((g+1)>>1)*8;                                        \
        _Pragma("unroll")                                                    \
        for (int i = 0; i < 8; ++i)                                          \
          abuf[(g+1)&1][i] = cohld16(np_ + (nb_+i)*32);                      \
        WAITV(8);                                                            \
      } else { WAITV(0); }                                                   \
      const int sg_ = g & 1;                                                 \
      const int kbb_ = (g >> 1) * 8;                                         \
      _Pragma("unroll")                                                      \
      for (int kk = 0; kk < 8; ++kk) {                                       \
        const int kb = kbb_ + kk;                                            \
        _Pragma("unroll")                                                    \
        for (int mt = 0; mt < 4; ++mt) {                                     \
          short8 wf = *(const short8*)&Wl[sg_][kb*4 + q][mt*16 + ln][0];     \
          ACC[mt] = __builtin_amdgcn_mfma_f32_16x16x32_bf16(                 \
              wf, abuf[g&1][kk], ACC[mt], 0, 0, 0);                          \
        }                                                                    \
      }                                                                      \
    } }

// in-lane epilogue. MODE 0: sv = x[b][TV]; 1: none; 2: sv = SVO (o value).
// OSLOT != 0 (role1): accumulate head partial fc.h and atomicAdd per batch.
// Every wave drains its stores/atomics before the caller's barrier.
#define EPI16(ACC, MODE, TV, SVO, HOUT, OSLOT)                               \
  { float sv = 0.f;                                                          \
    if ((MODE) == 0)      sv = ldf(x, (long)(B0 + bl)*TT + (TV), dt);        \
    else if ((MODE) == 2) sv = (SVO);                                        \
    float po = 0.f;                                                          \
    _Pragma("unroll")                                                        \
    for (int mt = 0; mt < 4; ++mt) {                                         \
      const int u = mt*4 + q;                                                \
      float gi = ACC[mt][0] + bs[u*4+0];                                     \
      float gf = ACC[mt][1] + bs[u*4+1];                                     \
      float gg = ACC[mt][2] + bs[u*4+2];                                     \
      float go = ACC[mt][3] + bs[u*4+3];                                     \
      if ((MODE) != 1) {                                                     \
        gi += sv*wih[u*4+0]; gf += sv*wih[u*4+1];                            \
        gg += sv*wih[u*4+2]; go += sv*wih[u*4+3];                            \
      }                                                                      \
      const float I = 1.f/(1.f+expf(-gi));                                   \
      const float F = 1.f/(1.f+expf(-gf));                                   \
      const float G = tanhf(gg);                                             \
      const float O = 1.f/(1.f+expf(-go));                                   \
      const float cn = F*cst[mt] + I*G;                                      \
      cst[mt] = cn;                                                          \
      const short hb16 = f2bf(O * tanhf(cn));                                \
      hbuf[bl][u] = hb16;                                                    \
      if ((OSLOT) != (float*)0) po += fwk[mt] * bf2f(hb16);                  \
    }                                                                        \
    if ((OSLOT) != (float*)0) {                                              \
      po += __shfl_xor(po, 16); po += __shfl_xor(po, 32);                    \
      if (lane < 16) atomicAdd((float*)(OSLOT) + bl, po);                    \
    }                                                                        \
    __syncthreads();                                                         \
    if (tid < 256) {                                                         \
      const int b_ = tid >> 1, hf_ = tid & 1;                                \
      short8 hv8 = *(const short8*)&hbuf[b_][hf_*8];                         \
      cohst16((HOUT) + (long)(B0 + b_)*512 + U0 + hf_*8, hv8);               \
    }                                                                        \
    asm volatile("s_waitcnt vmcnt(0)" ::: "memory"); }

// bounded spin: breaks after SPIN_CAP iterations instead of hanging.
#define SPIN(COND)                                                           \
  { long guard_ = 0;                                                         \
    while (COND) {                                                           \
      __builtin_amdgcn_s_sleep(1);                                           \
      if (++guard_ > SPIN_CAP) break;                                        \
    } }

// barrier: 8 groups of 16, per-group release line (r14 protocol, no fence)
#define GBAR()                                                               \
  { __syncthreads();                                                         \
    ++ph;                                                                    \
    if (tid == 0) {                                                          \
      asm volatile("s_waitcnt vmcnt(0)" ::: "memory");                       \
      __hip_atomic_fetch_add(grpArr, 1, __ATOMIC_RELAXED,                    \
                             __HIP_MEMORY_SCOPE_SYSTEM);                     \
      if (isMaster) {                                                        \
        SPIN(__hip_atomic_load(grpArr, __ATOMIC_RELAXED,                     \
                               __HIP_MEMORY_SCOPE_SYSTEM) < ph * 16);        \
        __hip_atomic_fetch_add(ctr, 1, __ATOMIC_RELAXED,                     \
                               __HIP_MEMORY_SCOPE_SYSTEM);                   \
        SPIN(__hip_atomic_load(ctr, __ATOMIC_RELAXED,                        \
                               __HIP_MEMORY_SCOPE_SYSTEM) < ph * 8);         \
        __hip_atomic_store(grpRel, ph, __ATOMIC_RELAXED,                     \
                           __HIP_MEMORY_SCOPE_SYSTEM);                       \
      } else {                                                               \
        SPIN(__hip_atomic_load(grpRel, __ATOMIC_RELAXED,                     \
                               __HIP_MEMORY_SCOPE_SYSTEM) < ph);             \
      }                                                                      \
    }                                                                        \
    __syncthreads(); }

  // ---- one-time staging: warmup weights + biases + head col ----
  if (role == 0) {
    STAGE16(0, Whh0);
    BIAS16(b_ih0, b_hh0, w_ih0);
  } else {
    STAGE16(0, Wih1); STAGE16(1, Whh1);
    BIAS16(b_ih1, b_hh1, (const void*)0);
    FWLOAD(fc_w);
  }
  const float fcb  = ldf(fc_b, 0, dt);
  const float pfcb = ldf(pfc_b, 0, dt);
  __syncthreads();

  // ---- warmup: phase t = L0(t) on role0 || L1(t-1) on role1 ----
  for (int t = 0; t < TT; ++t) {
    if (role == 0) {
      floatx4 a[4]; ZACC(a);
      GSEG1N(h0c, a);
      EPI16(a, 0, t, 0.f, h0n, (float*)0);
    } else if (t > 0) {
      floatx4 a[4]; ZACC(a);
      GSEG2N(h0c, h1c, a);
      EPI16(a, 1, 0, 0.f, h1n, (float*)0);
    }
    GBAR();
    { short* t_ = h0c; h0c = h0n; h0n = t_; }
    if (t > 0) { short* t_ = h1c; h1c = h1n; h1n = t_; }
  }
  // final L1(511): also emits head partials for step 0 (fc head)
  if (role == 1) {
    floatx4 a[4]; ZACC(a);
    GSEG2N(h0c, h1c, a);
    EPI16(a, 1, 0, 0.f, h1n, oA + B0);
  }
  GBAR();
  { short* t_ = h1c; h1c = h1n; h1n = t_; }

  // ---- transition: stage decode weights + biases (block-local) ----
  if (role == 0) {
    STAGE16(0, pWhh0);
    BIAS16(pb_ih0, pb_hh0, pw_ih0);
  } else {
    STAGE16(0, pWih1); STAGE16(1, pWhh1);
    BIAS16(pb_ih1, pb_hh1, (const void*)0);
    FWLOAD(pfc_w);
  }
  __syncthreads();

  // ---- decode: 63 steps, 2 barriers each; o via oacc partials ----
  for (int s = 1; s < FUT; ++s) {
    if (role == 0) {
      // read o(s-1) = sum of role1 partials + head bias; write dout col s-1
      const float ob_ = (s == 1) ? fcb : pfcb;
      const float o_ = __hip_atomic_load(
          oA + (long)(s-1)*BB + B0 + bl,
          __ATOMIC_RELAXED, __HIP_MEMORY_SCOPE_SYSTEM) + ob_;
      if (ug == 0 && lane < 16)
        dout[(long)(B0 + bl)*FUT + (s-1)] = o_;
      floatx4 a[4]; ZACC(a);
      GSEG1N(h0c, a);
      EPI16(a, 2, 0, o_, h0n, (float*)0);
    }
    GBAR();
    { short* t_ = h0c; h0c = h0n; h0n = t_; }
    if (role == 1) {
      floatx4 a[4]; ZACC(a);
      GSEG2N(h0c, h1c, a);
      EPI16(a, 1, 0, 0.f, h1n, oA + (long)s*BB + B0);
    }
    GBAR();
    { short* t_ = h1c; h1c = h1n; h1n = t_; }
  }
  // tail: emit dout col 63
  if (role == 0 && ug == 0 && lane < 16) {
    const float o_ = __hip_atomic_load(
        oA + (long)(FUT-1)*BB + B0 + bl,
        __ATOMIC_RELAXED, __HIP_MEMORY_SCOPE_SYSTEM) + pfcb;
    dout[(long)(B0 + bl)*FUT + (FUT-1)] = o_;
  }
#undef STAGE16
#undef BIAS16
#undef FWLOAD
#undef ZACC
#undef GSEG1N
#undef GSEG2N
#undef EPI16
#undef SPIN
#undef GBAR
}

extern "C" void kernel_launch(void* const* d_in, const int* in_sizes, int n_in,
                              void* d_out, int out_size, void* d_ws, size_t ws_size,
                              hipStream_t stream) {
  float* dout = (float*)d_out;

  static const int exp_sizes[22] = {
    131072, 1, 2048, 1048576, 2048, 2048, 1048576, 1048576, 2048, 2048,
    512, 1, 2048, 1048576, 2048, 2048, 1048576, 1048576, 2048, 2048, 512, 1};
  int code = -1, m = 0;
  if (n_in != 22) { code = 0; m = n_in & 127; }
  else {
    for (int i = 0; i < 22; ++i)
      if (in_sizes[i] != exp_sizes[i]) { code = 1; m = i; break; }
  }
  if (code < 0 && out_size != BB * FUT) { code = 6; m = (out_size >> 8) & 127; }
  if (code < 0 && (d_ws == nullptr || ws_size < NEED_WS)) {
    code = 2; m = (int)(ws_size >> 20); if (m > 127) m = 127;
  }
  if (code >= 0) {
    float v = ldexpf(1.f + (float)m / 128.f, 20 + code);
    beacon_kernel<<<dim3(1), dim3(64), 0, stream>>>(dout, v);
    return;
  }

  const void* x      = d_in[0];
  const void* w_ih0  = d_in[2];
  const void* w_hh0  = d_in[3];
  const void* b_ih0  = d_in[4];
  const void* b_hh0  = d_in[5];
  const void* w_ih1  = d_in[6];
  const void* w_hh1  = d_in[7];
  const void* b_ih1  = d_in[8];
  const void* b_hh1  = d_in[9];
  const void* fc_w   = d_in[10];
  const void* fc_b   = d_in[11];
  const void* pw_ih0 = d_in[12];
  const void* pw_hh0 = d_in[13];
  const void* pb_ih0 = d_in[14];
  const void* pb_hh0 = d_in[15];
  const void* pw_ih1 = d_in[16];
  const void* pw_hh1 = d_in[17];
  const void* pb_ih1 = d_in[18];
  const void* pb_hh1 = d_in[19];
  const void* pfc_w  = d_in[20];
  const void* pfc_b  = d_in[21];

  char* ws = (char*)d_ws;
  Hdr* hdr = (Hdr*)ws;
  int* ctr = (int*)(ws + OFF_CTR);
  short* Wc[6];
  for (int i = 0; i < 6; ++i) Wc[i] = (short*)(ws + OFF_W + (size_t)i*WSZ);
  short* H0a = (short*)(ws + OFF_H);
  short* H0b = (short*)(ws + OFF_H + HSZ);
  short* H1a = (short*)(ws + OFF_H + 2*HSZ);
  short* H1b = (short*)(ws + OFF_H + 3*HSZ);
  float* oA  = (float*)(ws + OFF_OA);

  hipMemsetAsync(ws, 0, 8192, stream);          // hdr + barrier counters
  hipMemsetAsync(H0a, 0, HSZ, stream);
  hipMemsetAsync(H1a, 0, HSZ, stream);
  hipMemsetAsync(oA, 0, OASZ, stream);          // head accumulators
  probe1_kernel<<<dim3(1), dim3(256), 0, stream>>>(w_hh0, hdr);

  dim3 cg(1024), cb(256);
  cvt_kernel<<<cg, cb, 0, stream>>>(w_hh0,  Wc[0], hdr);
  cvt_kernel<<<cg, cb, 0, stream>>>(w_ih1,  Wc[1], hdr);
  cvt_kernel<<<cg, cb, 0, stream>>>(w_hh1,  Wc[2], hdr);
  cvt_kernel<<<cg, cb, 0, stream>>>(pw_hh0, Wc[3], hdr);
  cvt_kernel<<<cg, cb, 0, stream>>>(pw_ih1, Wc[4], hdr);
  cvt_kernel<<<cg, cb, 0, stream>>>(pw_hh1, Wc[5], hdr);

  lstm_persist<<<dim3(NBLK), dim3(512), 0, stream>>>(
      x, w_ih0, b_ih0, b_hh0, b_ih1, b_hh1, fc_w, fc_b,
      pw_ih0, pb_ih0, pb_hh0, pb_ih1, pb_hh1, pfc_w, pfc_b,
      Wc[0], Wc[1], Wc[2], Wc[3], Wc[4], Wc[5],
      H0a, H0b, H1a, H1b, oA, ctr, hdr, dout);
}

// Round 6
// 6714.045 us; speedup vs baseline: 1.5890x; 1.0735x over previous
//
#include <hip/hip_runtime.h>
#include <hip/hip_bf16.h>

// Problem constants (B=256, T=512, H=512, IN=1, future=64)
#define TT  512
#define BB  256
#define HH  512
#define FUT 64
#define NBLK 128           // 2 roles x 32 unit-groups x 2 batch-groups

// Output dtype FP32. Beacons: float 2^(20+code)*(1+m/128):
//  0: n_in!=22  1: in_sizes mismatch @m  2: ws too small  6: out_size wrong
// r18: barrier-free pipeline. r17 showed ~8us of each 11.3us phase was the
// 2-level global barrier (3 chained IC round trips x 639 phases). Replaced
// with per-step producer-consumer counters (drain->add publish, poll->sync
// consume; fence-free r14 coherence: all h via sc0sc1, counters via system
// atomics on IC):
//   pub0[g]: role0 published h0(g)          (32 adds; role1+role0 poll)
//   pub1[g]: role1 published h1(g)          (role1 peers poll)
//   cons1[g]: role1 finished READING h0(g)  (ring-4 backpressure for role0)
//   opub[s]: head value o(s) accumulated    (role0 decode polls)
// h0 = 4-deep ring, h1 = 2-deep ring. Batch-groups fully independent
// (separate counter banks). Role0's short chain leaves the critical path;
// warmup cost ~= role1 chain alone. Spin caps: hang -> passed:false.
// r17 kept: 512 thr / 8 waves, layer-split roles, operand-swapped MFMA,
// in-lane EPI, distributed head partials.

struct Hdr { int dtflag; };

typedef __attribute__((ext_vector_type(8))) short short8;
typedef __attribute__((ext_vector_type(4))) float floatx4;

#define OFF_FLG   4096
#define OFF_W     20480
#define WSZ       ((size_t)2048*512*2)          // 2MB bf16 matrix
#define OFF_H0    (OFF_W + 6*WSZ)               // h0 ring: 4 x 256KB
#define HSZ       ((size_t)BB*HH*2)             // 256KB bf16 state
#define OFF_H1    (OFF_H0 + 4*HSZ)              // h1 ring: 2 x 256KB
#define OFF_OA    (OFF_H1 + 2*HSZ)              // o accumulators
#define OASZ      ((size_t)FUT*BB*4)            // 64KB fp32
#define NEED_WS   (OFF_OA + OASZ)               // ~14.2MB

#define SPIN_CAP  (1L << 22)

__device__ __forceinline__ float bf2f(short s) {
  unsigned u = ((unsigned)(unsigned short)s) << 16;
  return __builtin_bit_cast(float, u);
}
__device__ __forceinline__ short f2bf(float f) {
  unsigned u = __builtin_bit_cast(unsigned, f);
  u = u + 0x7FFFu + ((u >> 16) & 1u);
  return (short)(u >> 16);
}
__device__ __forceinline__ float ldf(const void* p, long i, int dt) {
  return dt ? ((const float*)p)[i] : bf2f(((const short*)p)[i]);
}
// 16B coherence-point load/store: dwordx4 with sc0 sc1 (bypass L1/L2,
// IC is the coherence point). Result not ready until manual WAITV.
__device__ __forceinline__ short8 cohld16(const short* p) {
  short8 v;
  asm volatile("global_load_dwordx4 %0, %1, off sc0 sc1"
               : "=v"(v) : "v"(p));
  return v;
}
__device__ __forceinline__ void cohst16(short* p, short8 v) {
  asm volatile("global_store_dwordx4 %0, %1, off sc0 sc1"
               :: "v"(p), "v"(v) : "memory");
}
// counted wait + hard scheduling fence (rule #18: keep MFMA below the wait)
#define WAITV(N) do { asm volatile("s_waitcnt vmcnt(" #N ")" ::: "memory"); \
                      __builtin_amdgcn_sched_barrier(0); } while (0)

__global__ void beacon_kernel(float* dout, float v) {
  if (threadIdx.x == 0) dout[0] = v;
}

__global__ __launch_bounds__(256) void probe1_kernel(const void* w, Hdr* hdr) {
  const int tid = threadIdx.x;
  const short* s = (const short*)w;
  float mx = 0.f;
  #pragma unroll
  for (int i = 0; i < 16; ++i) {
    float v = fabsf(bf2f(s[tid * 16 + i]));
    if (!(v == v)) v = 1e30f;
    mx = fmaxf(mx, v);
  }
  #pragma unroll
  for (int off = 32; off > 0; off >>= 1) mx = fmaxf(mx, __shfl_down(mx, off));
  __shared__ float wmax[4];
  if ((tid & 63) == 0) wmax[tid >> 6] = mx;
  __syncthreads();
  if (tid == 0) {
    float m = fmaxf(fmaxf(wmax[0], wmax[1]), fmaxf(wmax[2], wmax[3]));
    hdr->dtflag = (m > 1000.f) ? 1 : 0;
  }
}

__global__ __launch_bounds__(256) void cvt_kernel(const void* src, short* dst,
                                                  const Hdr* hdr) {
  const int dt = hdr->dtflag;
  const long i = ((long)blockIdx.x * 256 + threadIdx.x);
  if (dt) {
    const float4 v = ((const float4*)src)[i];
    short4 o;
    o.x = f2bf(v.x); o.y = f2bf(v.y); o.z = f2bf(v.z); o.w = f2bf(v.w);
    ((short4*)dst)[i] = o;
  } else {
    ((short4*)dst)[i] = ((const short4*)src)[i];
  }
}

// Persistent 2-layer LSTM, layer-split roles, barrier-free counter pipeline.
__global__ __launch_bounds__(512, 1) void lstm_persist(
    const void* __restrict__ x,
    const void* __restrict__ w_ih0, const void* __restrict__ b_ih0,
    const void* __restrict__ b_hh0, const void* __restrict__ b_ih1,
    const void* __restrict__ b_hh1, const void* __restrict__ fc_w,
    const void* __restrict__ fc_b,  const void* __restrict__ pw_ih0,
    const void* __restrict__ pb_ih0, const void* __restrict__ pb_hh0,
    const void* __restrict__ pb_ih1, const void* __restrict__ pb_hh1,
    const void* __restrict__ pfc_w, const void* __restrict__ pfc_b,
    const short* __restrict__ Whh0, const short* __restrict__ Wih1,
    const short* __restrict__ Whh1, const short* __restrict__ pWhh0,
    const short* __restrict__ pWih1, const short* __restrict__ pWhh1,
    short* H0R, short* H1R, float* oA, int* flg,
    const Hdr* __restrict__ hdr, float* __restrict__ dout)
{
  const int dt  = hdr->dtflag;
  const int tid = threadIdx.x;
  const int role = blockIdx.x & 1;         // 0 = layer0, 1 = layer1
  const int bg   = (blockIdx.x >> 1) & 1;  // 0..1
  const int ug   = blockIdx.x >> 2;        // 0..31
  const int U0   = ug * 16;
  const int B0   = bg * 128;

  // per-bg counter bank (batch-groups are fully independent)
  int* F     = flg + bg * 2048;
  int* pub0  = F;          // [0..575]
  int* pub1  = F + 576;    // [0..575]
  int* cons1 = F + 1152;   // [0..575]
  int* opub  = F + 1728;   // [0..63]

  // 128KB weights: [slot][kseg(64)][row(64)][8]; row = unit_local*4 + gate.
  // role0 uses slot0; role1 uses slot0(ih)+slot1(hh).
  __shared__ __align__(16) short Wl[2][64][64][8];
  __shared__ __align__(16) short hbuf[128][16];  // 4KB h repack
  __shared__ float bs[64];                       // bias, idx = u*4+gate
  __shared__ float wih[64];                      // w_ih col (L0 only)

  const int lane = tid & 63;
  const int wv   = tid >> 6;           // wave 0..7: 16-batch slice each
  const int ln   = lane & 15;          // batch-in-tile AND W-row-in-tile
  const int q    = lane >> 4;          // k-slice / unit-in-quad
  const int bl   = wv*16 + ln;         // batch-in-block 0..127
  const long abase = (long)(B0 + bl) * 512 + q*8;

  // per-lane cell state: unit = U0 + mt*4 + q, batch = B0 + bl
  float cst[4] = {0.f, 0.f, 0.f, 0.f};
  float fwk[4] = {0.f, 0.f, 0.f, 0.f};   // head weight col (role1)

// ring slot bases (131072 shorts = one 256KB h state)
#define H0S(G) (H0R + (size_t)((G) & 3) * 131072)
#define H1S(G) (H1R + (size_t)((G) & 1) * 131072)

// bounded spin (anti-hang): protocol failure -> garbage, not dead container
#define SPIN(COND)                                                           \
  { long guard_ = 0;                                                         \
    while (COND) {                                                           \
      __builtin_amdgcn_s_sleep(1);                                           \
      if (++guard_ > SPIN_CAP) break;                                        \
    } }
#define POLL(P, T)                                                           \
  SPIN(__hip_atomic_load((P), __ATOMIC_RELAXED,                              \
                         __HIP_MEMORY_SCOPE_SYSTEM) < (T))
#define FADD(P)                                                              \
  __hip_atomic_fetch_add((P), 1, __ATOMIC_RELAXED,                           \
                         __HIP_MEMORY_SCOPE_SYSTEM)

// stage one 64KB slot, global-coalesced
#define STAGE16(SLOT, WG)                                                    \
  for (int i = tid; i < 4096; i += 512) {                                    \
    const int ks_ = i & 63, r_ = i >> 6;                                     \
    const long gr = (long)((r_ & 3) * 512 + U0 + (r_ >> 2)) * 512 + ks_ * 8; \
    *(short8*)&Wl[SLOT][ks_][r_][0] = *(const short8*)((WG) + gr);           \
  }

#define BIAS16(B1, B2, WIHP)                                                 \
  if (tid < 64) {                                                            \
    const long j = (long)(tid & 3) * 512 + U0 + (tid >> 2);                  \
    bs[tid] = ldf((B1), j, dt) + ldf((B2), j, dt);                           \
    wih[tid] = (WIHP) ? ldf((const void*)(WIHP), j, dt) : 0.f;               \
  }

#define FWLOAD(FWP)                                                          \
  { _Pragma("unroll")                                                        \
    for (int mt = 0; mt < 4; ++mt)                                           \
      fwk[mt] = ldf((FWP), U0 + mt*4 + q, dt); }

#define ZACC(A)                                                              \
  _Pragma("unroll") for (int mt_ = 0; mt_ < 4; ++mt_)                        \
    A[mt_] = (floatx4){0.f, 0.f, 0.f, 0.f};

// single-stream pass: 16 kb, 2 groups of 8, 2-deep
#define GSEG1N(AP, ACC)                                                      \
  { const short* ap_ = (AP) + abase;                                         \
    short8 abuf[2][8];                                                       \
    _Pragma("unroll")                                                        \
    for (int i = 0; i < 8; ++i) abuf[0][i] = cohld16(ap_ + i*32);            \
    _Pragma("unroll")                                                        \
    for (int g = 0; g < 2; ++g) {                                            \
      if (g == 0) {                                                          \
        _Pragma("unroll")                                                    \
        for (int i = 0; i < 8; ++i)                                          \
          abuf[1][i] = cohld16(ap_ + (8+i)*32);                              \
        WAITV(8);                                                            \
      } else { WAITV(0); }                                                   \
      _Pragma("unroll")                                                      \
      for (int kk = 0; kk < 8; ++kk) {                                       \
        const int kb = g*8 + kk;                                             \
        _Pragma("unroll")                                                    \
        for (int mt = 0; mt < 4; ++mt) {                                     \
          short8 wf = *(const short8*)&Wl[0][kb*4 + q][mt*16 + ln][0];       \
          ACC[mt] = __builtin_amdgcn_mfma_f32_16x16x32_bf16(                 \
              wf, abuf[g][kk], ACC[mt], 0, 0, 0);                            \
        }                                                                    \
      }                                                                      \
    } }

// dual-stream pass: Wl[0]*h(AP0) + Wl[1]*h(AP1); 4 groups of 8, 2-deep
#define GSEG2N(AP0, AP1, ACC)                                                \
  { const short* p0_ = (AP0) + abase;                                        \
    const short* p1_ = (AP1) + abase;                                        \
    short8 abuf[2][8];                                                       \
    _Pragma("unroll")                                                        \
    for (int i = 0; i < 8; ++i) abuf[0][i] = cohld16(p0_ + i*32);            \
    _Pragma("unroll")                                                        \
    for (int g = 0; g < 4; ++g) {                                            \
      if (g < 3) {                                                           \
        const short* np_ = ((g+1)&1) ? p1_ : p0_;                            \
        const int nb_ = ((g+1)>>1)*8;                                        \
        _Pragma("unroll")                                                    \
        for (int i = 0; i < 8; ++i)                                          \
          abuf[(g+1)&1][i] = cohld16(np_ + (nb_+i)*32);                      \
        WAITV(8);                                                            \
      } else { WAITV(0); }                                                   \
      const int sg_ = g & 1;                                                 \
      const int kbb_ = (g >> 1) * 8;                                         \
      _Pragma("unroll")                                                      \
      for (int kk = 0; kk < 8; ++kk) {                                       \
        const int kb = kbb_ + kk;                                            \
        _Pragma("unroll")                                                    \
        for (int mt = 0; mt < 4; ++mt) {                                     \
          short8 wf = *(const short8*)&Wl[sg_][kb*4 + q][mt*16 + ln][0];     \
          ACC[mt] = __builtin_amdgcn_mfma_f32_16x16x32_bf16(                 \
              wf, abuf[g&1][kk], ACC[mt], 0, 0, 0);                          \
        }                                                                    \
      }                                                                      \
    } }

// in-lane epilogue. MODE 0: sv = x[b][TV]; 1: none; 2: sv = SVO (o value).
// OSLOT != 0: accumulate head partial fc.h, atomicAdd per batch.
// Ends fully drained (per-wave vmcnt0) + block-synced, so the caller's
// tid0 publish-add is ordered after ALL waves' stores/atomics hit IC.
#define EPI16(ACC, MODE, TV, SVO, HOUT, OSLOT)                               \
  { float sv = 0.f;                                                          \
    if ((MODE) == 0)      sv = ldf(x, (long)(B0 + bl)*TT + (TV), dt);        \
    else if ((MODE) == 2) sv = (SVO);                                        \
    float po = 0.f;                                                          \
    _Pragma("unroll")                                                        \
    for (int mt = 0; mt < 4; ++mt) {                                         \
      const int u = mt*4 + q;                                                \
      float gi = ACC[mt][0] + bs[u*4+0];                                     \
      float gf = ACC[mt][1] + bs[u*4+1];                                     \
      float gg = ACC[mt][2] + bs[u*4+2];                                     \
      float go = ACC[mt][3] + bs[u*4+3];                                     \
      if ((MODE) != 1) {                                                     \
        gi += sv*wih[u*4+0]; gf += sv*wih[u*4+1];                            \
        gg += sv*wih[u*4+2]; go += sv*wih[u*4+3];                            \
      }                                                                      \
      const float I = 1.f/(1.f+expf(-gi));                                   \
      const float F = 1.f/(1.f+expf(-gf));                                   \
      const float G = tanhf(gg);                                             \
      const float O = 1.f/(1.f+expf(-go));                                   \
      const float cn = F*cst[mt] + I*G;                                      \
      cst[mt] = cn;                                                          \
      const short hb16 = f2bf(O * tanhf(cn));                                \
      hbuf[bl][u] = hb16;                                                    \
      if ((OSLOT) != (float*)0) po += fwk[mt] * bf2f(hb16);                  \
    }                                                                        \
    if ((OSLOT) != (float*)0) {                                              \
      po += __shfl_xor(po, 16); po += __shfl_xor(po, 32);                    \
      if (lane < 16) atomicAdd((float*)(OSLOT) + bl, po);                    \
    }                                                                        \
    __syncthreads();                                                         \
    if (tid < 256) {                                                         \
      const int b_ = tid >> 1, hf_ = tid & 1;                                \
      short8 hv8 = *(const short8*)&hbuf[b_][hf_*8];                         \
      cohst16((HOUT) + (long)(B0 + b_)*512 + U0 + hf_*8, hv8);               \
    }                                                                        \
    asm volatile("s_waitcnt vmcnt(0)" ::: "memory");                         \
    __syncthreads(); }

  // ---- one-time staging: warmup weights + biases + head col ----
  if (role == 0) {
    STAGE16(0, Whh0);
    BIAS16(b_ih0, b_hh0, w_ih0);
  } else {
    STAGE16(0, Wih1); STAGE16(1, Whh1);
    BIAS16(b_ih1, b_hh1, (const void*)0);
    FWLOAD(fc_w);
  }
  const float fcb  = ldf(fc_b, 0, dt);
  const float pfcb = ldf(pfc_b, 0, dt);
  __syncthreads();

  if (role == 0) {
    // ======== role0: L0 chain, runs ahead on the h0 ring ========
    for (int g = 0; g < TT; ++g) {
      if (tid == 0) {
        if (g > 0)  POLL(pub0 + g - 1, 32);     // peers published h0(g-1)
        if (g >= 4) POLL(cons1 + g - 4, 32);    // ring-4 backpressure
      }
      __syncthreads();
      floatx4 a[4]; ZACC(a);
      GSEG1N(H0S(g-1), a);
      EPI16(a, 0, g, 0.f, H0S(g), (float*)0);
      if (tid == 0) FADD(pub0 + g);
    }
    // transition: decode weights (block-local)
    STAGE16(0, pWhh0);
    BIAS16(pb_ih0, pb_hh0, pw_ih0);
    __syncthreads();
    // decode L0: consumes o(s-1) from role1's head partials
    for (int s = 1; s < FUT; ++s) {
      const int g = 511 + s;
      if (tid == 0) {
        POLL(pub0 + g - 1, 32);
        POLL(cons1 + g - 4, 32);
        POLL(opub + s - 1, 32);
      }
      __syncthreads();
      const float ob_ = (s == 1) ? fcb : pfcb;
      const float o_ = __hip_atomic_load(
          oA + (long)(s-1)*BB + B0 + bl,
          __ATOMIC_RELAXED, __HIP_MEMORY_SCOPE_SYSTEM) + ob_;
      if (ug == 0 && lane < 16)
        dout[(long)(B0 + bl)*FUT + (s-1)] = o_;
      floatx4 a[4]; ZACC(a);
      GSEG1N(H0S(g-1), a);
      EPI16(a, 2, 0, o_, H0S(g), (float*)0);
      if (tid == 0) FADD(pub0 + g);
    }
    // tail: emit dout col 63
    if (tid == 0) POLL(opub + FUT - 1, 32);
    __syncthreads();
    if (ug == 0 && lane < 16) {
      const float o_ = __hip_atomic_load(
          oA + (long)(FUT-1)*BB + B0 + bl,
          __ATOMIC_RELAXED, __HIP_MEMORY_SCOPE_SYSTEM) + pfcb;
      dout[(long)(B0 + bl)*FUT + (FUT-1)] = o_;
    }
  } else {
    // ======== role1: L1 chain (the critical path) ========
    for (int g = 0; g < TT; ++g) {
      if (tid == 0) {
        POLL(pub0 + g, 32);                     // h0(g) ready
        if (g > 0) POLL(pub1 + g - 1, 32);      // peers' h1(g-1)
      }
      __syncthreads();
      floatx4 a[4]; ZACC(a);
      GSEG2N(H0S(g), H1S(g-1), a);
      __syncthreads();                          // all waves done reading h0(g)
      if (tid == 0) FADD(cons1 + g);
      float* os_ = (g == TT-1) ? (oA + B0) : (float*)0;  // head @ last step
      EPI16(a, 1, 0, 0.f, H1S(g), os_);
      if (tid == 0) {
        FADD(pub1 + g);
        if (g == TT-1) FADD(opub + 0);
      }
    }
    // transition: decode weights + decode head col (block-local)
    STAGE16(0, pWih1); STAGE16(1, pWhh1);
    BIAS16(pb_ih1, pb_hh1, (const void*)0);
    FWLOAD(pfc_w);
    __syncthreads();
    for (int s = 1; s < FUT; ++s) {
      const int g = 511 + s;
      if (tid == 0) {
        POLL(pub0 + g, 32);
        POLL(pub1 + g - 1, 32);
      }
      __syncthreads();
      floatx4 a[4]; ZACC(a);
      GSEG2N(H0S(g), H1S(g-1), a);
      __syncthreads();
      if (tid == 0) FADD(cons1 + g);
      EPI16(a, 1, 0, 0.f, H1S(g), oA + (long)s*BB + B0);
      if (tid == 0) { FADD(pub1 + g); FADD(opub + s); }
    }
  }
#undef STAGE16
#undef BIAS16
#undef FWLOAD
#undef ZACC
#undef GSEG1N
#undef GSEG2N
#undef EPI16
#undef SPIN
#undef POLL
#undef FADD
#undef H0S
#undef H1S
}

extern "C" void kernel_launch(void* const* d_in, const int* in_sizes, int n_in,
                              void* d_out, int out_size, void* d_ws, size_t ws_size,
                              hipStream_t stream) {
  float* dout = (float*)d_out;

  static const int exp_sizes[22] = {
    131072, 1, 2048, 1048576, 2048, 2048, 1048576, 1048576, 2048, 2048,
    512, 1, 2048, 1048576, 2048, 2048, 1048576, 1048576, 2048, 2048, 512, 1};
  int code = -1, m = 0;
  if (n_in != 22) { code = 0; m = n_in & 127; }
  else {
    for (int i = 0; i < 22; ++i)
      if (in_sizes[i] != exp_sizes[i]) { code = 1; m = i; break; }
  }
  if (code < 0 && out_size != BB * FUT) { code = 6; m = (out_size >> 8) & 127; }
  if (code < 0 && (d_ws == nullptr || ws_size < NEED_WS)) {
    code = 2; m = (int)(ws_size >> 20); if (m > 127) m = 127;
  }
  if (code >= 0) {
    float v = ldexpf(1.f + (float)m / 128.f, 20 + code);
    beacon_kernel<<<dim3(1), dim3(64), 0, stream>>>(dout, v);
    return;
  }

  const void* x      = d_in[0];
  const void* w_ih0  = d_in[2];
  const void* w_hh0  = d_in[3];
  const void* b_ih0  = d_in[4];
  const void* b_hh0  = d_in[5];
  const void* w_ih1  = d_in[6];
  const void* w_hh1  = d_in[7];
  const void* b_ih1  = d_in[8];
  const void* b_hh1  = d_in[9];
  const void* fc_w   = d_in[10];
  const void* fc_b   = d_in[11];
  const void* pw_ih0 = d_in[12];
  const void* pw_hh0 = d_in[13];
  const void* pb_ih0 = d_in[14];
  const void* pb_hh0 = d_in[15];
  const void* pw_ih1 = d_in[16];
  const void* pw_hh1 = d_in[17];
  const void* pb_ih1 = d_in[18];
  const void* pb_hh1 = d_in[19];
  const void* pfc_w  = d_in[20];
  const void* pfc_b  = d_in[21];

  char* ws = (char*)d_ws;
  Hdr* hdr = (Hdr*)ws;
  int* flg = (int*)(ws + OFF_FLG);
  short* Wc[6];
  for (int i = 0; i < 6; ++i) Wc[i] = (short*)(ws + OFF_W + (size_t)i*WSZ);
  short* H0R = (short*)(ws + OFF_H0);
  short* H1R = (short*)(ws + OFF_H1);
  float* oA  = (float*)(ws + OFF_OA);

  hipMemsetAsync(ws, 0, 20480, stream);         // hdr + counter banks
  hipMemsetAsync(H0R, 0, 4*HSZ + 2*HSZ + OASZ, stream);  // rings + oacc
  probe1_kernel<<<dim3(1), dim3(256), 0, stream>>>(w_hh0, hdr);

  dim3 cg(1024), cb(256);
  cvt_kernel<<<cg, cb, 0, stream>>>(w_hh0,  Wc[0], hdr);
  cvt_kernel<<<cg, cb, 0, stream>>>(w_ih1,  Wc[1], hdr);
  cvt_kernel<<<cg, cb, 0, stream>>>(w_hh1,  Wc[2], hdr);
  cvt_kernel<<<cg, cb, 0, stream>>>(pw_hh0, Wc[3], hdr);
  cvt_kernel<<<cg, cb, 0, stream>>>(pw_ih1, Wc[4], hdr);
  cvt_kernel<<<cg, cb, 0, stream>>>(pw_hh1, Wc[5], hdr);

  lstm_persist<<<dim3(NBLK), dim3(512), 0, stream>>>(
      x, w_ih0, b_ih0, b_hh0, b_ih1, b_hh1, fc_w, fc_b,
      pw_ih0, pb_ih0, pb_hh0, pb_ih1, pb_hh1, pfc_w, pfc_b,
      Wc[0], Wc[1], Wc[2], Wc[3], Wc[4], Wc[5],
      H0R, H1R, oA, flg, hdr, dout);
}